// Round 2
// baseline (203.270 us; speedup 1.0000x reference)
//
#include <hip/hip_runtime.h>
#include <math.h>

// Fixed-point LeNet, B=2048. R11: three-kernel pipeline, k2 back to full parallelism.
// k1: conv1+pool1 (R8/R9 structure, untouched) + ALL weight pre-quant in block 0
//     (fc1/fc2 transposed+quantized, conv2 padded [cc][28] x256) into d_ws.
// k2: conv2+pool2 ONLY, 1 image/block (grid=2048 — R10's 2-img/block halved the
//     grid and regressed 70->84 us; conv2 is LDS-latency-bound and needs waves).
//     Staging is now pure float4 copies from pre-quantized ws (no rintf/div/mod).
// k3: fc1+fc2+log_softmax, one wave per image, shfl-only tail (R10, works).
//
// Output layout (fp32, concatenated flat in reference return order):
//   logp[2048,10], conv1_in[2048,784], conv1_out[2048,5760],
//   conv2_in[2048,1440], conv2_out[2048,1280], fc1_in[2048,320],
//   fc1_out[2048,50], fc2_in[2048,50], fc2_out[2048,10]

#define NB 2048

#define OFF_LOGP   0
#define OFF_C1IN   (OFF_LOGP  + NB*10)
#define OFF_C1OUT  (OFF_C1IN  + NB*784)
#define OFF_C2IN   (OFF_C1OUT + NB*5760)
#define OFF_C2OUT  (OFF_C2IN  + NB*1440)
#define OFF_FC1IN  (OFF_C2OUT + NB*1280)
#define OFF_FC1OUT (OFF_FC1IN + NB*320)
#define OFF_FC2IN  (OFF_FC1OUT+ NB*50)
#define OFF_FC2OUT (OFF_FC2IN + NB*50)

#define MAGIC_F 12582912.0f   // 1.5 * 2^23

// Workspace layout (floats): pre-quantized weights, written by k1 block 0.
#define WS_WT1 0         // [320][64] transposed fw1: wT1[k*64+j]=clamp(quant(fw1[j][k])), j>=50 -> 0
#define WS_B1  20480     // [64]
#define WS_WT2 20544     // [50][16] transposed fw2: wT2[k*16+j], j>=10 -> 0
#define WS_B2  21344     // [16]
#define WS_CW2 21360     // [20*10][28] padded conv2 rows, quant(w)*256 (col>=25 -> 0)
#define WS_CB2 26960     // [20] quant(b)*256   (total 26980 floats = 108 KB)

__device__ __forceinline__ float clamp8(float v) {
    return __builtin_amdgcn_fmed3f(v, -8.0f, 7.0f);
}

// ---------------- K1: conv1 + pool1 (+ weight prep in block 0) ----------------
// grid = 2*NB, block = 256. blockIdx>>1 = img, blockIdx&1 = co-half (5 co each).
// 240 active tasks: t = co_l*48 + i*2 + jh. bit1(t)==i&1 -> pool partner t^2.
__global__ __launch_bounds__(256, 3)
void k1_conv1(const float* __restrict__ x,
              const float* __restrict__ cw1, const float* __restrict__ cb1,
              const float* __restrict__ cw2, const float* __restrict__ cb2,
              const float* __restrict__ fw1, const float* __restrict__ fb1,
              const float* __restrict__ fw2, const float* __restrict__ fb2,
              float* __restrict__ ws,
              float* __restrict__ out)
{
    __shared__ __align__(16) float s_w1[140];   // [5][28] padded, quant(w)*256
    __shared__ float s_b1[5];
    __shared__ __align__(16) float s_x[784];

    const int t    = threadIdx.x;
    const int img  = blockIdx.x >> 1;
    const int half = blockIdx.x & 1;

    if (t < 125) s_w1[(t / 25) * 28 + (t % 25)] = rintf(cw1[half * 125 + t] * 256.0f);
    if (t < 5)   s_b1[t] = rintf(cb1[half * 5 + t] * 256.0f);

    const float* xg = x + (size_t)img * 784;
    float* c1in_g = out + OFF_C1IN + (size_t)img * 784;
    for (int i = t; i < 784; i += 256) {
        float v = rintf(xg[i] * 256.0f) * (1.0f / 256.0f);
        s_x[i] = v;
        if (half == 0) c1in_g[i] = v;
    }
    __syncthreads();

    if (t < 240) {
        const int co_l = t / 48;
        const int co   = half * 5 + co_l;
        const int r    = t % 48;
        const int i    = r >> 1;
        const int jh   = r & 1;                 // cols [12*jh, 12*jh+12)

        float wreg[28];
        {
            const float* wb = s_w1 + co_l * 28;
            #pragma unroll
            for (int k = 0; k < 7; k++) {
                float4 v4 = *(const float4*)(wb + 4 * k);
                wreg[4*k] = v4.x; wreg[4*k+1] = v4.y; wreg[4*k+2] = v4.z; wreg[4*k+3] = v4.w;
            }
        }

        float acc[12];
        #pragma unroll
        for (int j = 0; j < 12; j++) acc[j] = MAGIC_F;   // magic-biased accumulator

        #pragma unroll
        for (int p = 0; p < 5; p++) {
            float xr[16];
            const float* row = &s_x[(i + p) * 28 + 12 * jh];
            #pragma unroll
            for (int k = 0; k < 4; k++) {
                float4 v4 = *(const float4*)(row + 4 * k);
                xr[4*k] = v4.x; xr[4*k+1] = v4.y; xr[4*k+2] = v4.z; xr[4*k+3] = v4.w;
            }
            #pragma unroll
            for (int q = 0; q < 5; q++) {
                float w = wreg[p * 5 + q];
                #pragma unroll
                for (int j = 0; j < 12; j++)
                    acc[j] = fmaf(xr[q + j], w, acc[j]);   // mul+round+add in 1 op
            }
        }
        const float C = MAGIC_F - s_b1[co_l];   // exact (b256 integer, same exponent)
        float v[12];
        #pragma unroll
        for (int j = 0; j < 12; j++) v[j] = (acc[j] - C) * (1.0f / 256.0f);  // exact grid

        float* gdst = out + OFF_C1OUT + (size_t)img * 5760 + co * 576 + i * 24 + 12 * jh;
        #pragma unroll
        for (int k = 0; k < 3; k++) {
            float4 st = { v[4*k], v[4*k+1], v[4*k+2], v[4*k+3] };
            *(float4*)(gdst + 4 * k) = st;
        }

        float m[6];
        #pragma unroll
        for (int j2 = 0; j2 < 6; j2++) m[j2] = fmaxf(v[2*j2], v[2*j2+1]);
        float pm[6];
        #pragma unroll
        for (int j2 = 0; j2 < 6; j2++) pm[j2] = __shfl_xor(m[j2], 2);

        if ((i & 1) == 0) {
            float pr[6];
            #pragma unroll
            for (int j2 = 0; j2 < 6; j2++)
                pr[j2] = fmaxf(fmaxf(m[j2], pm[j2]), 0.0f);
            float* g = out + OFF_C2IN + (size_t)img * 1440 + co * 144 + (i >> 1) * 12 + 6 * jh;
            #pragma unroll
            for (int k = 0; k < 3; k++) {
                float2 st = { pr[2*k], pr[2*k+1] };
                *(float2*)(g + 2 * k) = st;
            }
        }
    }

    // ---- weight pre-quant (block 0 only; hidden under the other 4095 blocks).
    // Stream-ordered: k2/k3 launch after k1 completes, so visibility is guaranteed.
    if (blockIdx.x == 0) {
        for (int idx = t; idx < 20480; idx += 256) {       // wT1[320][64]
            int k = idx >> 6, j = idx & 63;
            float v = 0.0f;
            if (j < 50) v = clamp8(rintf(fw1[j * 320 + k] * 256.0f) * (1.0f / 256.0f));
            ws[WS_WT1 + idx] = v;
        }
        for (int idx = t; idx < 800; idx += 256) {         // wT2[50][16]
            int k = idx >> 4, j = idx & 15;
            float v = 0.0f;
            if (j < 10) v = clamp8(rintf(fw2[j * 50 + k] * 256.0f) * (1.0f / 256.0f));
            ws[WS_WT2 + idx] = v;
        }
        if (t < 64) ws[WS_B1 + t] = (t < 50) ? clamp8(rintf(fb1[t] * 256.0f) * (1.0f / 256.0f)) : 0.0f;
        if (t < 16) ws[WS_B2 + t] = (t < 10) ? clamp8(rintf(fb2[t] * 256.0f) * (1.0f / 256.0f)) : 0.0f;
        for (int idx = t; idx < 5600; idx += 256) {        // conv2 padded [cc][28], x256
            int cc = idx / 28, col = idx % 28;
            float v = 0.0f;
            if (col < 25) v = rintf(cw2[cc * 25 + col] * 256.0f);
            ws[WS_CW2 + idx] = v;
        }
        if (t < 20) ws[WS_CB2 + t] = rintf(cb2[t] * 256.0f);
    }
}

// ---------------- K2: conv2 + pool2 only ----------------
// block=320 (5 waves), 1 image/block, grid=NB (R9 parallelism — conv2 is
// LDS-latency-bound, needs wave count). Staging = float4 copies from ws.
// conv2 task: t -> (co=t/16, i=(t/2)%8, jh=t&1), 4 outputs per thread.
__global__ __launch_bounds__(320, 2)
void k2_conv2(const float* __restrict__ ws, float* __restrict__ out)
{
    __shared__ __align__(16) float s_w2[5600];   // [co][ci][28] padded rows, x256
    __shared__ float s_b2[20];
    __shared__ __align__(16) float s_p1[1440];   // conv2 input

    const int t   = threadIdx.x;
    const int img = blockIdx.x;

    {   // weights: pre-quantized, pre-padded -> pure vector copy (1400 float4)
        const float4* wsrc = (const float4*)(ws + WS_CW2);
        float4* wdst = (float4*)s_w2;
        for (int i = t; i < 1400; i += 320) wdst[i] = wsrc[i];
    }
    if (t < 20) s_b2[t] = ws[WS_CB2 + t];
    {   // conv2 input (written by k1): 360 float4
        const float4* p1g = (const float4*)(out + OFF_C2IN + (size_t)img * 1440);
        float4* pdst = (float4*)s_p1;
        for (int i = t; i < 360; i += 320) pdst[i] = p1g[i];
    }
    __syncthreads();

    const int co = t >> 4;
    const int i  = (t >> 1) & 7;
    const int jh = t & 1;              // j base = 4*jh
    const float C2 = MAGIC_F - s_b2[co];

    float acc[4] = { MAGIC_F, MAGIC_F, MAGIC_F, MAGIC_F };
    for (int ci = 0; ci < 10; ci++) {
        float wreg[28];
        {
            const float* wb = s_w2 + (co * 10 + ci) * 28;
            #pragma unroll
            for (int k = 0; k < 7; k++) {
                float4 v4 = *(const float4*)(wb + 4 * k);
                wreg[4*k] = v4.x; wreg[4*k+1] = v4.y; wreg[4*k+2] = v4.z; wreg[4*k+3] = v4.w;
            }
        }
        const float* xb = s_p1 + ci * 144 + jh * 4;
        #pragma unroll
        for (int p = 0; p < 5; p++) {
            const float* row = xb + (i + p) * 12;
            float4 a4 = *(const float4*)(row);
            float4 b4 = *(const float4*)(row + 4);
            float xr[8] = { a4.x, a4.y, a4.z, a4.w, b4.x, b4.y, b4.z, b4.w };
            #pragma unroll
            for (int q = 0; q < 5; q++) {
                float w = wreg[p * 5 + q];
                #pragma unroll
                for (int j = 0; j < 4; j++)
                    acc[j] = fmaf(xr[q + j], w, acc[j]);   // mul+round+add in 1 op
            }
        }
    }
    float v[4];
    #pragma unroll
    for (int j = 0; j < 4; j++) v[j] = (acc[j] - C2) * (1.0f / 256.0f);  // exact grid

    {   // conv2_output
        float4 st = { v[0], v[1], v[2], v[3] };
        *(float4*)(out + OFF_C2OUT + (size_t)img * 1280 + co * 64 + i * 8 + jh * 4) = st;
    }

    // pool2 via shfl (row pair i, i^1 are lanes t, t^2 — same wave)
    float m0 = fmaxf(v[0], v[1]);
    float m1 = fmaxf(v[2], v[3]);
    float pm0 = __shfl_xor(m0, 2);
    float pm1 = __shfl_xor(m1, 2);
    if ((i & 1) == 0) {
        float r0 = fmaxf(fmaxf(m0, pm0), 0.0f);
        float r1 = fmaxf(fmaxf(m1, pm1), 0.0f);
        int o = co * 16 + (i >> 1) * 4 + jh * 2;   // [co][4][4]
        out[OFF_FC1IN + (size_t)img * 320 + o]     = r0;
        out[OFF_FC1IN + (size_t)img * 320 + o + 1] = r1;
    }
}

// ---------------- K3: fc1 + fc2 + log_softmax, one wave per image ----------------
// block=256 (4 waves = 4 images), grid = NB/4 = 512.
// fc1: lane j<50 owns output j; x broadcast from LDS (same-addr = free),
// weights pre-transposed -> one coalesced 256B load per k. fc2 + softmax via shfl.
__global__ __launch_bounds__(256)
void k3_fc(const float* __restrict__ ws, float* __restrict__ out)
{
    __shared__ float s_x[4][320];

    const int t    = threadIdx.x;
    const int wv   = t >> 6;
    const int lane = t & 63;
    const int img  = blockIdx.x * 4 + wv;

    const float* xg = out + OFF_FC1IN + (size_t)img * 320;   // written by k2
    #pragma unroll
    for (int r = 0; r < 5; r++)
        s_x[wv][lane + 64 * r] = clamp8(xg[lane + 64 * r]);  // round_max(quant(x)) (already on grid)
    __syncthreads();

    // ---- fc1 ----
    float acc = ws[WS_B1 + lane];
    #pragma unroll 8
    for (int k = 0; k < 320; k++)
        acc = fmaf(s_x[wv][k], ws[WS_WT1 + k * 64 + lane], acc);
    float o1 = rintf(clamp8(acc) * 256.0f) * (1.0f / 256.0f);
    float r1 = fmaxf(o1, 0.0f);
    if (lane < 50) {
        out[OFF_FC1OUT + (size_t)img * 50 + lane] = o1;
        out[OFF_FC2IN  + (size_t)img * 50 + lane] = r1;
    }
    float yc = clamp8(r1);                 // valid on lanes 0..49

    // ---- fc2 (y broadcast via shfl with uniform index -> readlane) ----
    float acc2 = ws[WS_B2 + (lane & 15)];
    #pragma unroll 10
    for (int k = 0; k < 50; k++) {
        float yk = __shfl(yc, k);
        acc2 = fmaf(yk, ws[WS_WT2 + k * 16 + (lane & 15)], acc2);
    }
    float o2 = rintf(clamp8(acc2) * 256.0f) * (1.0f / 256.0f);
    if (lane < 10) out[OFF_FC2OUT + (size_t)img * 10 + lane] = o2;

    // ---- log_softmax across lanes 0..9 (16-lane butterfly; group 0 valid) ----
    float v = (lane < 10) ? o2 : -3.0e38f;
    #pragma unroll
    for (int d = 1; d < 16; d <<= 1)
        v = fmaxf(v, __shfl_xor(v, d, 16));
    float e = (lane < 10) ? expf(o2 - v) : 0.0f;
    #pragma unroll
    for (int d = 1; d < 16; d <<= 1)
        e += __shfl_xor(e, d, 16);
    float lse = v + logf(e);
    if (lane < 10) out[OFF_LOGP + (size_t)img * 10 + lane] = o2 - lse;
}

extern "C" void kernel_launch(void* const* d_in, const int* in_sizes, int n_in,
                              void* d_out, int out_size, void* d_ws, size_t ws_size,
                              hipStream_t stream) {
    const float* x   = (const float*)d_in[0];
    const float* cw1 = (const float*)d_in[1];
    const float* cb1 = (const float*)d_in[2];
    const float* cw2 = (const float*)d_in[3];
    const float* cb2 = (const float*)d_in[4];
    const float* fw1 = (const float*)d_in[5];
    const float* fb1 = (const float*)d_in[6];
    const float* fw2 = (const float*)d_in[7];
    const float* fb2 = (const float*)d_in[8];
    float* o  = (float*)d_out;
    float* ws = (float*)d_ws;

    k1_conv1<<<2 * NB, 256, 0, stream>>>(x, cw1, cb1, cw2, cb2, fw1, fb1, fw2, fb2, ws, o);
    k2_conv2<<<NB, 320, 0, stream>>>(ws, o);
    k3_fc   <<<NB / 4, 256, 0, stream>>>(ws, o);
}

// Round 3
// 179.564 us; speedup vs baseline: 1.1320x; 1.1320x over previous
//
#include <hip/hip_runtime.h>
#include <math.h>

// Fixed-point LeNet, B=2048. R12.
// k1: conv1+pool1 (R8/R9 conv structure) + weight pre-quant SPREAD over blocks
//     0..51 (R11 put ~27k prep elements in block 0 alone -> serial straggler
//     tail, stretched k1 by ~40us. Now: 1 coalesced fc1 row per block, ~2 iters
//     each, fully hidden under the other 4000 blocks).
// k2: conv2+pool2, 640-thread blocks, TWO images in parallel (waves 0-4 img A,
//     waves 5-9 img B). One 22.4KB weight stage serves 2 images; 34KB LDS ->
//     3 blocks x 10 waves = 30 waves/CU potential (was 25). Grid 1024.
//     (R10's regression was thread-SERIAL 2-img; this is thread-PARALLEL.)
// k3: fc1+fc2+log_softmax, one wave per image, shfl-only tail (proven).
//
// Output layout (fp32, concatenated flat in reference return order):
//   logp[2048,10], conv1_in[2048,784], conv1_out[2048,5760],
//   conv2_in[2048,1440], conv2_out[2048,1280], fc1_in[2048,320],
//   fc1_out[2048,50], fc2_in[2048,50], fc2_out[2048,10]

#define NB 2048

#define OFF_LOGP   0
#define OFF_C1IN   (OFF_LOGP  + NB*10)
#define OFF_C1OUT  (OFF_C1IN  + NB*784)
#define OFF_C2IN   (OFF_C1OUT + NB*5760)
#define OFF_C2OUT  (OFF_C2IN  + NB*1440)
#define OFF_FC1IN  (OFF_C2OUT + NB*1280)
#define OFF_FC1OUT (OFF_FC1IN + NB*320)
#define OFF_FC2IN  (OFF_FC1OUT+ NB*50)
#define OFF_FC2OUT (OFF_FC2IN + NB*50)

#define MAGIC_F 12582912.0f   // 1.5 * 2^23

// Workspace layout (floats): pre-quantized weights, written by k1 blocks 0..51.
#define WS_WT1 0         // [320][64] transposed fw1: wT1[k*64+j]=clamp(quant(fw1[j][k])), j>=50 -> 0
#define WS_B1  20480     // [64]
#define WS_WT2 20544     // [50][16] transposed fw2: wT2[k*16+j], j>=10 -> 0
#define WS_B2  21344     // [16]
#define WS_CW2 21360     // [20*10][28] padded conv2 rows, quant(w)*256 (col>=25 -> 0)
#define WS_CB2 26960     // [20] quant(b)*256   (total 26980 floats = 108 KB)

__device__ __forceinline__ float clamp8(float v) {
    return __builtin_amdgcn_fmed3f(v, -8.0f, 7.0f);
}

// ---------------- K1: conv1 + pool1 (+ spread weight prep) ----------------
// grid = 2*NB, block = 256. blockIdx>>1 = img, blockIdx&1 = co-half (5 co each).
// 240 active tasks: t = co_l*48 + i*2 + jh. bit1(t)==i&1 -> pool partner t^2.
__global__ __launch_bounds__(256, 3)
void k1_conv1(const float* __restrict__ x,
              const float* __restrict__ cw1, const float* __restrict__ cb1,
              const float* __restrict__ cw2, const float* __restrict__ cb2,
              const float* __restrict__ fw1, const float* __restrict__ fb1,
              const float* __restrict__ fw2, const float* __restrict__ fb2,
              float* __restrict__ ws,
              float* __restrict__ out)
{
    __shared__ __align__(16) float s_w1[140];   // [5][28] padded, quant(w)*256
    __shared__ float s_b1[5];
    __shared__ __align__(16) float s_x[784];

    const int t    = threadIdx.x;
    const int img  = blockIdx.x >> 1;
    const int half = blockIdx.x & 1;

    if (t < 125) s_w1[(t / 25) * 28 + (t % 25)] = rintf(cw1[half * 125 + t] * 256.0f);
    if (t < 5)   s_b1[t] = rintf(cb1[half * 5 + t] * 256.0f);

    const float* xg = x + (size_t)img * 784;
    float* c1in_g = out + OFF_C1IN + (size_t)img * 784;
    for (int i = t; i < 784; i += 256) {
        float v = rintf(xg[i] * 256.0f) * (1.0f / 256.0f);
        s_x[i] = v;
        if (half == 0) c1in_g[i] = v;
    }
    __syncthreads();

    if (t < 240) {
        const int co_l = t / 48;
        const int co   = half * 5 + co_l;
        const int r    = t % 48;
        const int i    = r >> 1;
        const int jh   = r & 1;                 // cols [12*jh, 12*jh+12)

        float wreg[28];
        {
            const float* wb = s_w1 + co_l * 28;
            #pragma unroll
            for (int k = 0; k < 7; k++) {
                float4 v4 = *(const float4*)(wb + 4 * k);
                wreg[4*k] = v4.x; wreg[4*k+1] = v4.y; wreg[4*k+2] = v4.z; wreg[4*k+3] = v4.w;
            }
        }

        float acc[12];
        #pragma unroll
        for (int j = 0; j < 12; j++) acc[j] = MAGIC_F;   // magic-biased accumulator

        #pragma unroll
        for (int p = 0; p < 5; p++) {
            float xr[16];
            const float* row = &s_x[(i + p) * 28 + 12 * jh];
            #pragma unroll
            for (int k = 0; k < 4; k++) {
                float4 v4 = *(const float4*)(row + 4 * k);
                xr[4*k] = v4.x; xr[4*k+1] = v4.y; xr[4*k+2] = v4.z; xr[4*k+3] = v4.w;
            }
            #pragma unroll
            for (int q = 0; q < 5; q++) {
                float w = wreg[p * 5 + q];
                #pragma unroll
                for (int j = 0; j < 12; j++)
                    acc[j] = fmaf(xr[q + j], w, acc[j]);   // mul+round+add in 1 op
            }
        }
        const float C = MAGIC_F - s_b1[co_l];   // exact (b256 integer, same exponent)
        float v[12];
        #pragma unroll
        for (int j = 0; j < 12; j++) v[j] = (acc[j] - C) * (1.0f / 256.0f);  // exact grid

        float* gdst = out + OFF_C1OUT + (size_t)img * 5760 + co * 576 + i * 24 + 12 * jh;
        #pragma unroll
        for (int k = 0; k < 3; k++) {
            float4 st = { v[4*k], v[4*k+1], v[4*k+2], v[4*k+3] };
            *(float4*)(gdst + 4 * k) = st;
        }

        float m[6];
        #pragma unroll
        for (int j2 = 0; j2 < 6; j2++) m[j2] = fmaxf(v[2*j2], v[2*j2+1]);
        float pm[6];
        #pragma unroll
        for (int j2 = 0; j2 < 6; j2++) pm[j2] = __shfl_xor(m[j2], 2);

        if ((i & 1) == 0) {
            float pr[6];
            #pragma unroll
            for (int j2 = 0; j2 < 6; j2++)
                pr[j2] = fmaxf(fmaxf(m[j2], pm[j2]), 0.0f);
            float* g = out + OFF_C2IN + (size_t)img * 1440 + co * 144 + (i >> 1) * 12 + 6 * jh;
            #pragma unroll
            for (int k = 0; k < 3; k++) {
                float2 st = { pr[2*k], pr[2*k+1] };
                *(float2*)(g + 2 * k) = st;
            }
        }
    }

    // ---- weight pre-quant, spread over blocks 0..51 (~1-2 extra iters each,
    // hidden under the other 4044 blocks' conv work; no barrier needed).
    // Stream-ordered: k2/k3 launch after k1 completes, so visibility is guaranteed.
    const int b = blockIdx.x;
    if (b < 50) {
        // wT1 row j=b: coalesced read fw1[b*320 + i], scattered (cheap) write.
        const float* src = fw1 + b * 320;
        for (int i = t; i < 320; i += 256)
            ws[WS_WT1 + i * 64 + b] = clamp8(rintf(src[i] * 256.0f) * (1.0f / 256.0f));
    } else if (b == 50) {
        // zero-fill wT1 cols 50..63
        for (int idx = t; idx < 320 * 14; idx += 256) {
            int i = idx / 14, j = 50 + idx % 14;
            ws[WS_WT1 + i * 64 + j] = 0.0f;
        }
        // wT2[50][16]
        for (int idx = t; idx < 800; idx += 256) {
            int k = idx >> 4, j = idx & 15;
            float v = 0.0f;
            if (j < 10) v = clamp8(rintf(fw2[j * 50 + k] * 256.0f) * (1.0f / 256.0f));
            ws[WS_WT2 + idx] = v;
        }
        if (t < 64) ws[WS_B1 + t] = (t < 50) ? clamp8(rintf(fb1[t] * 256.0f) * (1.0f / 256.0f)) : 0.0f;
        if (t < 16) ws[WS_B2 + t] = (t < 10) ? clamp8(rintf(fb2[t] * 256.0f) * (1.0f / 256.0f)) : 0.0f;
    } else if (b == 51) {
        // conv2 padded [cc][28], x256
        for (int idx = t; idx < 5600; idx += 256) {
            int cc = idx / 28, col = idx % 28;
            float v = 0.0f;
            if (col < 25) v = rintf(cw2[cc * 25 + col] * 256.0f);
            ws[WS_CW2 + idx] = v;
        }
        if (t < 20) ws[WS_CB2 + t] = rintf(cb2[t] * 256.0f);
    }
}

// ---------------- K2: conv2 + pool2 only ----------------
// block=640 (10 waves), 2 images in PARALLEL (waves 0-4 img A, 5-9 img B),
// grid=NB/2=1024. One weight stage per 2 images; staging = float4 copies.
// conv2 task: tt -> (co=tt/16, i=(tt/2)%8, jh=tt&1), 4 outputs per thread.
__global__ __launch_bounds__(640, 7)
void k2_conv2(const float* __restrict__ ws, float* __restrict__ out)
{
    __shared__ __align__(16) float s_w2[5600];     // [co][ci][28] padded rows, x256
    __shared__ float s_b2[20];
    __shared__ __align__(16) float s_p1[2 * 1440]; // conv2 input, 2 images

    const int t    = threadIdx.x;
    const int img0 = blockIdx.x * 2;

    {   // weights: pre-quantized, pre-padded -> pure vector copy (1400 float4)
        const float4* wsrc = (const float4*)(ws + WS_CW2);
        float4* wdst = (float4*)s_w2;
        for (int i = t; i < 1400; i += 640) wdst[i] = wsrc[i];
    }
    if (t < 20) s_b2[t] = ws[WS_CB2 + t];
    {   // conv2 input (written by k1): 720 float4, two contiguous images
        const float4* p1g = (const float4*)(out + OFF_C2IN + (size_t)img0 * 1440);
        float4* pdst = (float4*)s_p1;
        for (int i = t; i < 720; i += 640) pdst[i] = p1g[i];
    }
    __syncthreads();

    const int im  = t >= 320;          // wave-aligned image split
    const int tt  = t - im * 320;
    const int img = img0 + im;
    const int co = tt >> 4;
    const int i  = (tt >> 1) & 7;
    const int jh = tt & 1;             // j base = 4*jh
    const float C2 = MAGIC_F - s_b2[co];

    float acc[4] = { MAGIC_F, MAGIC_F, MAGIC_F, MAGIC_F };
    for (int ci = 0; ci < 10; ci++) {
        float wreg[28];
        {
            const float* wb = s_w2 + (co * 10 + ci) * 28;
            #pragma unroll
            for (int k = 0; k < 7; k++) {
                float4 v4 = *(const float4*)(wb + 4 * k);
                wreg[4*k] = v4.x; wreg[4*k+1] = v4.y; wreg[4*k+2] = v4.z; wreg[4*k+3] = v4.w;
            }
        }
        const float* xb = s_p1 + im * 1440 + ci * 144 + jh * 4;
        #pragma unroll
        for (int p = 0; p < 5; p++) {
            const float* row = xb + (i + p) * 12;
            float4 a4 = *(const float4*)(row);
            float4 b4 = *(const float4*)(row + 4);
            float xr[8] = { a4.x, a4.y, a4.z, a4.w, b4.x, b4.y, b4.z, b4.w };
            #pragma unroll
            for (int q = 0; q < 5; q++) {
                float w = wreg[p * 5 + q];
                #pragma unroll
                for (int j = 0; j < 4; j++)
                    acc[j] = fmaf(xr[q + j], w, acc[j]);   // mul+round+add in 1 op
            }
        }
    }
    float v[4];
    #pragma unroll
    for (int j = 0; j < 4; j++) v[j] = (acc[j] - C2) * (1.0f / 256.0f);  // exact grid

    {   // conv2_output
        float4 st = { v[0], v[1], v[2], v[3] };
        *(float4*)(out + OFF_C2OUT + (size_t)img * 1280 + co * 64 + i * 8 + jh * 4) = st;
    }

    // pool2 via shfl (row pair i, i^1 are lanes tt, tt^2 — same wave)
    float m0 = fmaxf(v[0], v[1]);
    float m1 = fmaxf(v[2], v[3]);
    float pm0 = __shfl_xor(m0, 2);
    float pm1 = __shfl_xor(m1, 2);
    if ((i & 1) == 0) {
        float r0 = fmaxf(fmaxf(m0, pm0), 0.0f);
        float r1 = fmaxf(fmaxf(m1, pm1), 0.0f);
        int o = co * 16 + (i >> 1) * 4 + jh * 2;   // [co][4][4]
        out[OFF_FC1IN + (size_t)img * 320 + o]     = r0;
        out[OFF_FC1IN + (size_t)img * 320 + o + 1] = r1;
    }
}

// ---------------- K3: fc1 + fc2 + log_softmax, one wave per image ----------------
// block=256 (4 waves = 4 images), grid = NB/4 = 512.
// fc1: lane j<50 owns output j; x broadcast from LDS (same-addr = free),
// weights pre-transposed -> one coalesced 256B load per k. fc2 + softmax via shfl.
__global__ __launch_bounds__(256)
void k3_fc(const float* __restrict__ ws, float* __restrict__ out)
{
    __shared__ float s_x[4][320];

    const int t    = threadIdx.x;
    const int wv   = t >> 6;
    const int lane = t & 63;
    const int img  = blockIdx.x * 4 + wv;

    const float* xg = out + OFF_FC1IN + (size_t)img * 320;   // written by k2
    #pragma unroll
    for (int r = 0; r < 5; r++)
        s_x[wv][lane + 64 * r] = clamp8(xg[lane + 64 * r]);  // round_max(quant(x)) (already on grid)
    __syncthreads();

    // ---- fc1 ----
    float acc = ws[WS_B1 + lane];
    #pragma unroll 8
    for (int k = 0; k < 320; k++)
        acc = fmaf(s_x[wv][k], ws[WS_WT1 + k * 64 + lane], acc);
    float o1 = rintf(clamp8(acc) * 256.0f) * (1.0f / 256.0f);
    float r1 = fmaxf(o1, 0.0f);
    if (lane < 50) {
        out[OFF_FC1OUT + (size_t)img * 50 + lane] = o1;
        out[OFF_FC2IN  + (size_t)img * 50 + lane] = r1;
    }
    float yc = clamp8(r1);                 // valid on lanes 0..49

    // ---- fc2 (y broadcast via shfl with uniform index -> readlane) ----
    float acc2 = ws[WS_B2 + (lane & 15)];
    #pragma unroll 10
    for (int k = 0; k < 50; k++) {
        float yk = __shfl(yc, k);
        acc2 = fmaf(yk, ws[WS_WT2 + k * 16 + (lane & 15)], acc2);
    }
    float o2 = rintf(clamp8(acc2) * 256.0f) * (1.0f / 256.0f);
    if (lane < 10) out[OFF_FC2OUT + (size_t)img * 10 + lane] = o2;

    // ---- log_softmax across lanes 0..9 (16-lane butterfly; group 0 valid) ----
    float v = (lane < 10) ? o2 : -3.0e38f;
    #pragma unroll
    for (int d = 1; d < 16; d <<= 1)
        v = fmaxf(v, __shfl_xor(v, d, 16));
    float e = (lane < 10) ? expf(o2 - v) : 0.0f;
    #pragma unroll
    for (int d = 1; d < 16; d <<= 1)
        e += __shfl_xor(e, d, 16);
    float lse = v + logf(e);
    if (lane < 10) out[OFF_LOGP + (size_t)img * 10 + lane] = o2 - lse;
}

extern "C" void kernel_launch(void* const* d_in, const int* in_sizes, int n_in,
                              void* d_out, int out_size, void* d_ws, size_t ws_size,
                              hipStream_t stream) {
    const float* x   = (const float*)d_in[0];
    const float* cw1 = (const float*)d_in[1];
    const float* cb1 = (const float*)d_in[2];
    const float* cw2 = (const float*)d_in[3];
    const float* cb2 = (const float*)d_in[4];
    const float* fw1 = (const float*)d_in[5];
    const float* fb1 = (const float*)d_in[6];
    const float* fw2 = (const float*)d_in[7];
    const float* fb2 = (const float*)d_in[8];
    float* o  = (float*)d_out;
    float* ws = (float*)d_ws;

    k1_conv1<<<2 * NB, 256, 0, stream>>>(x, cw1, cb1, cw2, cb2, fw1, fb1, fw2, fb2, ws, o);
    k2_conv2<<<NB / 2, 640, 0, stream>>>(ws, o);
    k3_fc   <<<NB / 4, 256, 0, stream>>>(ws, o);
}

// Round 4
// 167.641 us; speedup vs baseline: 1.2125x; 1.0711x over previous
//
#include <hip/hip_runtime.h>
#include <math.h>

// Fixed-point LeNet, B=2048. R13: fused conv pipeline.
// k12: conv1+pool1+conv2+pool2 in ONE 512-thread block per image.
//      pool1 output handed off via LDS (s_p1) — eliminates k2's 11.8MB c2in
//      re-read, its weight re-staging barrier, and one kernel ramp/drain.
//      R3 budget: fill(harness,50us) + k1(~47) + k2(49.4) + k3(~6); k1 and k2
//      are co-equal latency-bound kernels ~6x above VALU floor (~13us total
//      conv FLOPs). Fusion attacks the glue, keeps proven compute bodies.
//      2 barriers only; 8 waves/block, 32.5KB LDS -> 3-4 blocks/CU resident.
// k3:  fc1+fc2+log_softmax, one wave per image, shfl-only tail (proven).
// fc weight pre-quant spread over k12 blocks 0..50 (R12-proven hiding).
//
// Output layout (fp32, concatenated flat in reference return order):
//   logp[2048,10], conv1_in[2048,784], conv1_out[2048,5760],
//   conv2_in[2048,1440], conv2_out[2048,1280], fc1_in[2048,320],
//   fc1_out[2048,50], fc2_in[2048,50], fc2_out[2048,10]

#define NB 2048

#define OFF_LOGP   0
#define OFF_C1IN   (OFF_LOGP  + NB*10)
#define OFF_C1OUT  (OFF_C1IN  + NB*784)
#define OFF_C2IN   (OFF_C1OUT + NB*5760)
#define OFF_C2OUT  (OFF_C2IN  + NB*1440)
#define OFF_FC1IN  (OFF_C2OUT + NB*1280)
#define OFF_FC1OUT (OFF_FC1IN + NB*320)
#define OFF_FC2IN  (OFF_FC1OUT+ NB*50)
#define OFF_FC2OUT (OFF_FC2IN + NB*50)

#define MAGIC_F 12582912.0f   // 1.5 * 2^23

// Workspace layout (floats): pre-quantized fc weights, written by k12 blocks 0..50.
#define WS_WT1 0         // [320][64] transposed fw1: wT1[k*64+j]=clamp(quant(fw1[j][k])), j>=50 -> 0
#define WS_B1  20480     // [64]
#define WS_WT2 20544     // [50][16] transposed fw2: wT2[k*16+j], j>=10 -> 0
#define WS_B2  21344     // [16]  (total 21360 floats = 85.4 KB)

__device__ __forceinline__ float clamp8(float v) {
    return __builtin_amdgcn_fmed3f(v, -8.0f, 7.0f);
}

// ---------------- K12: conv1 + pool1 + conv2 + pool2, one block per image ----------------
// block=512 (8 waves), grid=NB.
// Phase 1 (conv1): 480 tasks t = co*48 + i*2 + jh (co 0..9, i 0..23, jh 0..1),
//   12 outputs each; pool partner is t^2 (same wave: xor of bit1 stays in a
//   64-lane window). Phase 2 (conv2): 320 tasks t -> (co=t/16, i=(t/2)%8, jh=t&1).
__global__ __launch_bounds__(512, 6)
void k12_convs(const float* __restrict__ x,
               const float* __restrict__ cw1, const float* __restrict__ cb1,
               const float* __restrict__ cw2, const float* __restrict__ cb2,
               const float* __restrict__ fw1, const float* __restrict__ fb1,
               const float* __restrict__ fw2, const float* __restrict__ fb2,
               float* __restrict__ ws,
               float* __restrict__ out)
{
    __shared__ __align__(16) float s_w1[280];    // [10][28] padded, quant(w)*256
    __shared__ float s_b1[10];
    __shared__ __align__(16) float s_w2[5600];   // [20*10][28] padded, quant(w)*256
    __shared__ float s_b2[20];
    __shared__ __align__(16) float s_x[784];     // quantized input image
    __shared__ __align__(16) float s_p1[1440];   // pool1 output = conv2 input (LDS handoff)

    const int t   = threadIdx.x;
    const int img = blockIdx.x;

    // ---- phase 0: stage everything (one barrier) ----
    if (t < 250)                 s_w1[(t/25)*28 + (t%25)] = rintf(cw1[t] * 256.0f);
    else if (t >= 256 && t < 266) s_b1[t - 256] = rintf(cb1[t - 256] * 256.0f);
    else if (t >= 288 && t < 308) s_b2[t - 288] = rintf(cb2[t - 288] * 256.0f);
    for (int idx = t; idx < 5000; idx += 512) {          // conv2 w: 20KB, L2-hit
        int cc = idx / 25, q = idx % 25;                 // cc = co*10+ci
        s_w2[cc * 28 + q] = rintf(cw2[idx] * 256.0f);
    }
    const float* xg = x + (size_t)img * 784;
    float* c1in_g = out + OFF_C1IN + (size_t)img * 784;
    for (int i = t; i < 784; i += 512) {
        float v = rintf(xg[i] * 256.0f) * (1.0f / 256.0f);
        s_x[i] = v;
        c1in_g[i] = v;
    }
    __syncthreads();

    // ---- phase 1: conv1 + pool1 ----
    if (t < 480) {
        const int co = t / 48;
        const int r  = t % 48;
        const int i  = r >> 1;
        const int jh = r & 1;                 // cols [12*jh, 12*jh+12)

        float wreg[28];
        {
            const float* wb = s_w1 + co * 28;
            #pragma unroll
            for (int k = 0; k < 7; k++) {
                float4 v4 = *(const float4*)(wb + 4 * k);
                wreg[4*k] = v4.x; wreg[4*k+1] = v4.y; wreg[4*k+2] = v4.z; wreg[4*k+3] = v4.w;
            }
        }

        float acc[12];
        #pragma unroll
        for (int j = 0; j < 12; j++) acc[j] = MAGIC_F;   // magic-biased accumulator

        #pragma unroll
        for (int p = 0; p < 5; p++) {
            float xr[16];
            const float* row = &s_x[(i + p) * 28 + 12 * jh];
            #pragma unroll
            for (int k = 0; k < 4; k++) {
                float4 v4 = *(const float4*)(row + 4 * k);
                xr[4*k] = v4.x; xr[4*k+1] = v4.y; xr[4*k+2] = v4.z; xr[4*k+3] = v4.w;
            }
            #pragma unroll
            for (int q = 0; q < 5; q++) {
                float w = wreg[p * 5 + q];
                #pragma unroll
                for (int j = 0; j < 12; j++)
                    acc[j] = fmaf(xr[q + j], w, acc[j]);   // mul+round+add in 1 op
            }
        }
        const float C = MAGIC_F - s_b1[co];   // exact (b256 integer, same exponent)
        float v[12];
        #pragma unroll
        for (int j = 0; j < 12; j++) v[j] = (acc[j] - C) * (1.0f / 256.0f);  // exact grid

        float* gdst = out + OFF_C1OUT + (size_t)img * 5760 + co * 576 + i * 24 + 12 * jh;
        #pragma unroll
        for (int k = 0; k < 3; k++) {
            float4 st = { v[4*k], v[4*k+1], v[4*k+2], v[4*k+3] };
            *(float4*)(gdst + 4 * k) = st;
        }

        float m[6];
        #pragma unroll
        for (int j2 = 0; j2 < 6; j2++) m[j2] = fmaxf(v[2*j2], v[2*j2+1]);
        float pm[6];
        #pragma unroll
        for (int j2 = 0; j2 < 6; j2++) pm[j2] = __shfl_xor(m[j2], 2);

        if ((i & 1) == 0) {
            float pr[6];
            #pragma unroll
            for (int j2 = 0; j2 < 6; j2++)
                pr[j2] = fmaxf(fmaxf(m[j2], pm[j2]), 0.0f);
            const int o = co * 144 + (i >> 1) * 12 + 6 * jh;
            float* g = out + OFF_C2IN + (size_t)img * 1440 + o;
            #pragma unroll
            for (int k = 0; k < 3; k++) {
                float2 st = { pr[2*k], pr[2*k+1] };
                *(float2*)(g + 2 * k) = st;
                s_p1[o + 2*k]     = pr[2*k];      // LDS handoff to conv2
                s_p1[o + 2*k + 1] = pr[2*k + 1];
            }
        }
    }
    __syncthreads();

    // ---- phase 2: conv2 + pool2 (R11-proven body, input from s_p1) ----
    if (t < 320) {
        const int co = t >> 4;
        const int i  = (t >> 1) & 7;
        const int jh = t & 1;              // j base = 4*jh
        const float C2 = MAGIC_F - s_b2[co];

        float acc[4] = { MAGIC_F, MAGIC_F, MAGIC_F, MAGIC_F };
        for (int ci = 0; ci < 10; ci++) {
            float wreg[28];
            {
                const float* wb = s_w2 + (co * 10 + ci) * 28;
                #pragma unroll
                for (int k = 0; k < 7; k++) {
                    float4 v4 = *(const float4*)(wb + 4 * k);
                    wreg[4*k] = v4.x; wreg[4*k+1] = v4.y; wreg[4*k+2] = v4.z; wreg[4*k+3] = v4.w;
                }
            }
            const float* xb = s_p1 + ci * 144 + jh * 4;
            #pragma unroll
            for (int p = 0; p < 5; p++) {
                const float* row = xb + (i + p) * 12;
                float4 a4 = *(const float4*)(row);
                float4 b4 = *(const float4*)(row + 4);
                float xr[8] = { a4.x, a4.y, a4.z, a4.w, b4.x, b4.y, b4.z, b4.w };
                #pragma unroll
                for (int q = 0; q < 5; q++) {
                    float w = wreg[p * 5 + q];
                    #pragma unroll
                    for (int j = 0; j < 4; j++)
                        acc[j] = fmaf(xr[q + j], w, acc[j]);   // mul+round+add in 1 op
                }
            }
        }
        float v[4];
        #pragma unroll
        for (int j = 0; j < 4; j++) v[j] = (acc[j] - C2) * (1.0f / 256.0f);  // exact grid

        {   // conv2_output
            float4 st = { v[0], v[1], v[2], v[3] };
            *(float4*)(out + OFF_C2OUT + (size_t)img * 1280 + co * 64 + i * 8 + jh * 4) = st;
        }

        // pool2 via shfl (row pair i, i^1 are lanes t, t^2 — same wave)
        float m0 = fmaxf(v[0], v[1]);
        float m1 = fmaxf(v[2], v[3]);
        float pm0 = __shfl_xor(m0, 2);
        float pm1 = __shfl_xor(m1, 2);
        if ((i & 1) == 0) {
            float r0 = fmaxf(fmaxf(m0, pm0), 0.0f);
            float r1 = fmaxf(fmaxf(m1, pm1), 0.0f);
            int o = co * 16 + (i >> 1) * 4 + jh * 2;   // [co][4][4]
            out[OFF_FC1IN + (size_t)img * 320 + o]     = r0;
            out[OFF_FC1IN + (size_t)img * 320 + o + 1] = r1;
        }
    }

    // ---- fc weight pre-quant, spread over blocks 0..50 (hidden; no barrier).
    // Stream-ordered: k3 launches after k12 completes, so visibility is guaranteed.
    const int b = blockIdx.x;
    if (b < 50) {
        // wT1 row j=b: coalesced read fw1[b*320 + i], scattered (cheap) write.
        const float* src = fw1 + b * 320;
        for (int i = t; i < 320; i += 512)
            ws[WS_WT1 + i * 64 + b] = clamp8(rintf(src[i] * 256.0f) * (1.0f / 256.0f));
    } else if (b == 50) {
        // zero-fill wT1 cols 50..63
        for (int idx = t; idx < 320 * 14; idx += 512) {
            int i = idx / 14, j = 50 + idx % 14;
            ws[WS_WT1 + i * 64 + j] = 0.0f;
        }
        // wT2[50][16]
        for (int idx = t; idx < 800; idx += 512) {
            int k = idx >> 4, j = idx & 15;
            float v = 0.0f;
            if (j < 10) v = clamp8(rintf(fw2[j * 50 + k] * 256.0f) * (1.0f / 256.0f));
            ws[WS_WT2 + idx] = v;
        }
        if (t < 64) ws[WS_B1 + t] = (t < 50) ? clamp8(rintf(fb1[t] * 256.0f) * (1.0f / 256.0f)) : 0.0f;
        if (t < 16) ws[WS_B2 + t] = (t < 10) ? clamp8(rintf(fb2[t] * 256.0f) * (1.0f / 256.0f)) : 0.0f;
    }
}

// ---------------- K3: fc1 + fc2 + log_softmax, one wave per image ----------------
// block=256 (4 waves = 4 images), grid = NB/4 = 512.
// fc1: lane j<50 owns output j; x broadcast from LDS (same-addr = free),
// weights pre-transposed -> one coalesced 256B load per k. fc2 + softmax via shfl.
__global__ __launch_bounds__(256)
void k3_fc(const float* __restrict__ ws, float* __restrict__ out)
{
    __shared__ float s_x[4][320];

    const int t    = threadIdx.x;
    const int wv   = t >> 6;
    const int lane = t & 63;
    const int img  = blockIdx.x * 4 + wv;

    const float* xg = out + OFF_FC1IN + (size_t)img * 320;   // written by k12
    #pragma unroll
    for (int r = 0; r < 5; r++)
        s_x[wv][lane + 64 * r] = clamp8(xg[lane + 64 * r]);  // round_max(quant(x)) (already on grid)
    __syncthreads();

    // ---- fc1 ----
    float acc = ws[WS_B1 + lane];
    #pragma unroll 8
    for (int k = 0; k < 320; k++)
        acc = fmaf(s_x[wv][k], ws[WS_WT1 + k * 64 + lane], acc);
    float o1 = rintf(clamp8(acc) * 256.0f) * (1.0f / 256.0f);
    float r1 = fmaxf(o1, 0.0f);
    if (lane < 50) {
        out[OFF_FC1OUT + (size_t)img * 50 + lane] = o1;
        out[OFF_FC2IN  + (size_t)img * 50 + lane] = r1;
    }
    float yc = clamp8(r1);                 // valid on lanes 0..49

    // ---- fc2 (y broadcast via shfl with uniform index -> readlane) ----
    float acc2 = ws[WS_B2 + (lane & 15)];
    #pragma unroll 10
    for (int k = 0; k < 50; k++) {
        float yk = __shfl(yc, k);
        acc2 = fmaf(yk, ws[WS_WT2 + k * 16 + (lane & 15)], acc2);
    }
    float o2 = rintf(clamp8(acc2) * 256.0f) * (1.0f / 256.0f);
    if (lane < 10) out[OFF_FC2OUT + (size_t)img * 10 + lane] = o2;

    // ---- log_softmax across lanes 0..9 (16-lane butterfly; group 0 valid) ----
    float v = (lane < 10) ? o2 : -3.0e38f;
    #pragma unroll
    for (int d = 1; d < 16; d <<= 1)
        v = fmaxf(v, __shfl_xor(v, d, 16));
    float e = (lane < 10) ? expf(o2 - v) : 0.0f;
    #pragma unroll
    for (int d = 1; d < 16; d <<= 1)
        e += __shfl_xor(e, d, 16);
    float lse = v + logf(e);
    if (lane < 10) out[OFF_LOGP + (size_t)img * 10 + lane] = o2 - lse;
}

extern "C" void kernel_launch(void* const* d_in, const int* in_sizes, int n_in,
                              void* d_out, int out_size, void* d_ws, size_t ws_size,
                              hipStream_t stream) {
    const float* x   = (const float*)d_in[0];
    const float* cw1 = (const float*)d_in[1];
    const float* cb1 = (const float*)d_in[2];
    const float* cw2 = (const float*)d_in[3];
    const float* cb2 = (const float*)d_in[4];
    const float* fw1 = (const float*)d_in[5];
    const float* fb1 = (const float*)d_in[6];
    const float* fw2 = (const float*)d_in[7];
    const float* fb2 = (const float*)d_in[8];
    float* o  = (float*)d_out;
    float* ws = (float*)d_ws;

    k12_convs<<<NB, 512, 0, stream>>>(x, cw1, cb1, cw2, cb2, fw1, fb1, fw2, fb2, ws, o);
    k3_fc    <<<NB / 4, 256, 0, stream>>>(ws, o);
}

// Round 5
// 157.736 us; speedup vs baseline: 1.2887x; 1.0628x over previous
//
#include <hip/hip_runtime.h>
#include <math.h>

// Fixed-point LeNet, B=2048. R14: fused k12 with ci-split conv2.
// R13 analysis: conv2 phase is LDS-pipe-bound (170 ds_read_b128/thread vs
// 1000 FMA — pipes 1:1 at m134 cycle costs). R14 conv2: task=(co,i,ci-half),
// full 8-col row per thread, shfl_xor(1) combines halves. LDS reads/thread
// 170->110 (-35%); weight reads conflict-free (8 addrs -> 8 bank groups);
// exact integer reduce (un-bias each magic partial before summing).
// conv1 / staging / fc-prep / k3 verbatim R13.
//
// Output layout (fp32, concatenated flat in reference return order):
//   logp[2048,10], conv1_in[2048,784], conv1_out[2048,5760],
//   conv2_in[2048,1440], conv2_out[2048,1280], fc1_in[2048,320],
//   fc1_out[2048,50], fc2_in[2048,50], fc2_out[2048,10]

#define NB 2048

#define OFF_LOGP   0
#define OFF_C1IN   (OFF_LOGP  + NB*10)
#define OFF_C1OUT  (OFF_C1IN  + NB*784)
#define OFF_C2IN   (OFF_C1OUT + NB*5760)
#define OFF_C2OUT  (OFF_C2IN  + NB*1440)
#define OFF_FC1IN  (OFF_C2OUT + NB*1280)
#define OFF_FC1OUT (OFF_FC1IN + NB*320)
#define OFF_FC2IN  (OFF_FC1OUT+ NB*50)
#define OFF_FC2OUT (OFF_FC2IN + NB*50)

#define MAGIC_F 12582912.0f   // 1.5 * 2^23

// Workspace layout (floats): pre-quantized fc weights, written by k12 blocks 0..50.
#define WS_WT1 0         // [320][64] transposed fw1: wT1[k*64+j]=clamp(quant(fw1[j][k])), j>=50 -> 0
#define WS_B1  20480     // [64]
#define WS_WT2 20544     // [50][16] transposed fw2: wT2[k*16+j], j>=10 -> 0
#define WS_B2  21344     // [16]  (total 21360 floats = 85.4 KB)

__device__ __forceinline__ float clamp8(float v) {
    return __builtin_amdgcn_fmed3f(v, -8.0f, 7.0f);
}

// ---------------- K12: conv1 + pool1 + conv2 + pool2, one block per image ----------------
// block=512 (8 waves), grid=NB.
// Phase 1 (conv1): 480 tasks t = co*48 + i*2 + jh, 12 outputs each; pool partner t^2.
// Phase 2 (conv2): 320 tasks t = (co*8+i)*2 + ch; ch = ci-half; 8 outputs each.
__global__ __launch_bounds__(512, 6)
void k12_convs(const float* __restrict__ x,
               const float* __restrict__ cw1, const float* __restrict__ cb1,
               const float* __restrict__ cw2, const float* __restrict__ cb2,
               const float* __restrict__ fw1, const float* __restrict__ fb1,
               const float* __restrict__ fw2, const float* __restrict__ fb2,
               float* __restrict__ ws,
               float* __restrict__ out)
{
    __shared__ __align__(16) float s_w1[280];    // [10][28] padded, quant(w)*256
    __shared__ float s_b1[10];
    __shared__ __align__(16) float s_w2[5600];   // [20*10][28] padded, quant(w)*256
    __shared__ float s_b2[20];
    __shared__ __align__(16) float s_x[784];     // quantized input image
    __shared__ __align__(16) float s_p1[1440];   // pool1 output = conv2 input (LDS handoff)

    const int t   = threadIdx.x;
    const int img = blockIdx.x;

    // ---- phase 0: stage everything (one barrier) ----
    if (t < 250)                 s_w1[(t/25)*28 + (t%25)] = rintf(cw1[t] * 256.0f);
    else if (t >= 256 && t < 266) s_b1[t - 256] = rintf(cb1[t - 256] * 256.0f);
    else if (t >= 288 && t < 308) s_b2[t - 288] = rintf(cb2[t - 288] * 256.0f);
    for (int idx = t; idx < 5000; idx += 512) {          // conv2 w: 20KB, L2-hit
        int cc = idx / 25, q = idx % 25;                 // cc = co*10+ci
        s_w2[cc * 28 + q] = rintf(cw2[idx] * 256.0f);
    }
    const float* xg = x + (size_t)img * 784;
    float* c1in_g = out + OFF_C1IN + (size_t)img * 784;
    for (int i = t; i < 784; i += 512) {
        float v = rintf(xg[i] * 256.0f) * (1.0f / 256.0f);
        s_x[i] = v;
        c1in_g[i] = v;
    }
    __syncthreads();

    // ---- phase 1: conv1 + pool1 (R13-proven) ----
    if (t < 480) {
        const int co = t / 48;
        const int r  = t % 48;
        const int i  = r >> 1;
        const int jh = r & 1;                 // cols [12*jh, 12*jh+12)

        float wreg[28];
        {
            const float* wb = s_w1 + co * 28;
            #pragma unroll
            for (int k = 0; k < 7; k++) {
                float4 v4 = *(const float4*)(wb + 4 * k);
                wreg[4*k] = v4.x; wreg[4*k+1] = v4.y; wreg[4*k+2] = v4.z; wreg[4*k+3] = v4.w;
            }
        }

        float acc[12];
        #pragma unroll
        for (int j = 0; j < 12; j++) acc[j] = MAGIC_F;   // magic-biased accumulator

        #pragma unroll
        for (int p = 0; p < 5; p++) {
            float xr[16];
            const float* row = &s_x[(i + p) * 28 + 12 * jh];
            #pragma unroll
            for (int k = 0; k < 4; k++) {
                float4 v4 = *(const float4*)(row + 4 * k);
                xr[4*k] = v4.x; xr[4*k+1] = v4.y; xr[4*k+2] = v4.z; xr[4*k+3] = v4.w;
            }
            #pragma unroll
            for (int q = 0; q < 5; q++) {
                float w = wreg[p * 5 + q];
                #pragma unroll
                for (int j = 0; j < 12; j++)
                    acc[j] = fmaf(xr[q + j], w, acc[j]);   // mul+round+add in 1 op
            }
        }
        const float C = MAGIC_F - s_b1[co];   // exact (b256 integer, same exponent)
        float v[12];
        #pragma unroll
        for (int j = 0; j < 12; j++) v[j] = (acc[j] - C) * (1.0f / 256.0f);  // exact grid

        float* gdst = out + OFF_C1OUT + (size_t)img * 5760 + co * 576 + i * 24 + 12 * jh;
        #pragma unroll
        for (int k = 0; k < 3; k++) {
            float4 st = { v[4*k], v[4*k+1], v[4*k+2], v[4*k+3] };
            *(float4*)(gdst + 4 * k) = st;
        }

        float m[6];
        #pragma unroll
        for (int j2 = 0; j2 < 6; j2++) m[j2] = fmaxf(v[2*j2], v[2*j2+1]);
        float pm[6];
        #pragma unroll
        for (int j2 = 0; j2 < 6; j2++) pm[j2] = __shfl_xor(m[j2], 2);

        if ((i & 1) == 0) {
            float pr[6];
            #pragma unroll
            for (int j2 = 0; j2 < 6; j2++)
                pr[j2] = fmaxf(fmaxf(m[j2], pm[j2]), 0.0f);
            const int o = co * 144 + (i >> 1) * 12 + 6 * jh;
            float* g = out + OFF_C2IN + (size_t)img * 1440 + o;
            #pragma unroll
            for (int k = 0; k < 3; k++) {
                float2 st = { pr[2*k], pr[2*k+1] };
                *(float2*)(g + 2 * k) = st;
                s_p1[o + 2*k]     = pr[2*k];      // LDS handoff to conv2
                s_p1[o + 2*k + 1] = pr[2*k + 1];
            }
        }
    }
    __syncthreads();

    // ---- phase 2: conv2 + pool2, ci-split (5 ci per thread, full 8-col row) ----
    if (t < 320) {
        const int ch = t & 1;              // ci-half: ci = 5*ch + cc
        const int rc = t >> 1;             // co*8 + i
        const int co = rc >> 3;
        const int i  = rc & 7;

        float acc[8];
        #pragma unroll
        for (int j = 0; j < 8; j++) acc[j] = MAGIC_F;

        #pragma unroll
        for (int cc = 0; cc < 5; cc++) {
            const int ci = ch * 5 + cc;
            float wreg[28];
            {
                const float* wb = s_w2 + (co * 10 + ci) * 28;
                #pragma unroll
                for (int k = 0; k < 7; k++) {
                    float4 v4 = *(const float4*)(wb + 4 * k);
                    wreg[4*k] = v4.x; wreg[4*k+1] = v4.y; wreg[4*k+2] = v4.z; wreg[4*k+3] = v4.w;
                }
            }
            const float* xb = s_p1 + ci * 144;
            #pragma unroll
            for (int p = 0; p < 5; p++) {
                const float* row = xb + (i + p) * 12;
                float4 a4 = *(const float4*)(row);
                float4 b4 = *(const float4*)(row + 4);
                float4 c4 = *(const float4*)(row + 8);
                float xr[12] = { a4.x, a4.y, a4.z, a4.w, b4.x, b4.y, b4.z, b4.w,
                                 c4.x, c4.y, c4.z, c4.w };
                #pragma unroll
                for (int q = 0; q < 5; q++) {
                    float w = wreg[p * 5 + q];
                    #pragma unroll
                    for (int j = 0; j < 8; j++)
                        acc[j] = fmaf(xr[q + j], w, acc[j]);   // mul+round+add in 1 op
                }
            }
        }

        // un-bias each partial (exact: same exponent as MAGIC), then integer-exact reduce
        float s[8];
        #pragma unroll
        for (int j = 0; j < 8; j++) s[j] = acc[j] - MAGIC_F;
        #pragma unroll
        for (int j = 0; j < 8; j++) s[j] += __shfl_xor(s[j], 1);   // partner = other ci-half

        const float b2 = s_b2[co];
        float v[8];
        #pragma unroll
        for (int j = 0; j < 8; j++) v[j] = (s[j] + b2) * (1.0f / 256.0f);  // exact grid

        // pool2 (computed by both ch lanes — identical values; partner i^1 = t^2)
        float m[4], pm[4];
        #pragma unroll
        for (int c = 0; c < 4; c++) m[c] = fmaxf(v[2*c], v[2*c+1]);
        #pragma unroll
        for (int c = 0; c < 4; c++) pm[c] = __shfl_xor(m[c], 2);

        if (ch == 0) {
            float4 st0 = { v[0], v[1], v[2], v[3] };
            float4 st1 = { v[4], v[5], v[6], v[7] };
            float* cdst = out + OFF_C2OUT + (size_t)img * 1280 + co * 64 + i * 8;
            *(float4*)(cdst)     = st0;
            *(float4*)(cdst + 4) = st1;

            if ((i & 1) == 0) {
                float4 pr = { fmaxf(fmaxf(m[0], pm[0]), 0.0f),
                              fmaxf(fmaxf(m[1], pm[1]), 0.0f),
                              fmaxf(fmaxf(m[2], pm[2]), 0.0f),
                              fmaxf(fmaxf(m[3], pm[3]), 0.0f) };
                *(float4*)(out + OFF_FC1IN + (size_t)img * 320 + co * 16 + (i >> 1) * 4) = pr;
            }
        }
    }

    // ---- fc weight pre-quant, spread over blocks 0..50 (hidden; no barrier).
    // Stream-ordered: k3 launches after k12 completes, so visibility is guaranteed.
    const int b = blockIdx.x;
    if (b < 50) {
        // wT1 row j=b: coalesced read fw1[b*320 + i], scattered (cheap) write.
        const float* src = fw1 + b * 320;
        for (int i = t; i < 320; i += 512)
            ws[WS_WT1 + i * 64 + b] = clamp8(rintf(src[i] * 256.0f) * (1.0f / 256.0f));
    } else if (b == 50) {
        // zero-fill wT1 cols 50..63
        for (int idx = t; idx < 320 * 14; idx += 512) {
            int i = idx / 14, j = 50 + idx % 14;
            ws[WS_WT1 + i * 64 + j] = 0.0f;
        }
        // wT2[50][16]
        for (int idx = t; idx < 800; idx += 512) {
            int k = idx >> 4, j = idx & 15;
            float v = 0.0f;
            if (j < 10) v = clamp8(rintf(fw2[j * 50 + k] * 256.0f) * (1.0f / 256.0f));
            ws[WS_WT2 + idx] = v;
        }
        if (t < 64) ws[WS_B1 + t] = (t < 50) ? clamp8(rintf(fb1[t] * 256.0f) * (1.0f / 256.0f)) : 0.0f;
        if (t < 16) ws[WS_B2 + t] = (t < 10) ? clamp8(rintf(fb2[t] * 256.0f) * (1.0f / 256.0f)) : 0.0f;
    }
}

// ---------------- K3: fc1 + fc2 + log_softmax, one wave per image ----------------
// block=256 (4 waves = 4 images), grid = NB/4 = 512.
// fc1: lane j<50 owns output j; x broadcast from LDS (same-addr = free),
// weights pre-transposed -> one coalesced 256B load per k. fc2 + softmax via shfl.
__global__ __launch_bounds__(256)
void k3_fc(const float* __restrict__ ws, float* __restrict__ out)
{
    __shared__ float s_x[4][320];

    const int t    = threadIdx.x;
    const int wv   = t >> 6;
    const int lane = t & 63;
    const int img  = blockIdx.x * 4 + wv;

    const float* xg = out + OFF_FC1IN + (size_t)img * 320;   // written by k12
    #pragma unroll
    for (int r = 0; r < 5; r++)
        s_x[wv][lane + 64 * r] = clamp8(xg[lane + 64 * r]);  // round_max(quant(x)) (already on grid)
    __syncthreads();

    // ---- fc1 ----
    float acc = ws[WS_B1 + lane];
    #pragma unroll 8
    for (int k = 0; k < 320; k++)
        acc = fmaf(s_x[wv][k], ws[WS_WT1 + k * 64 + lane], acc);
    float o1 = rintf(clamp8(acc) * 256.0f) * (1.0f / 256.0f);
    float r1 = fmaxf(o1, 0.0f);
    if (lane < 50) {
        out[OFF_FC1OUT + (size_t)img * 50 + lane] = o1;
        out[OFF_FC2IN  + (size_t)img * 50 + lane] = r1;
    }
    float yc = clamp8(r1);                 // valid on lanes 0..49

    // ---- fc2 (y broadcast via shfl with uniform index -> readlane) ----
    float acc2 = ws[WS_B2 + (lane & 15)];
    #pragma unroll 10
    for (int k = 0; k < 50; k++) {
        float yk = __shfl(yc, k);
        acc2 = fmaf(yk, ws[WS_WT2 + k * 16 + (lane & 15)], acc2);
    }
    float o2 = rintf(clamp8(acc2) * 256.0f) * (1.0f / 256.0f);
    if (lane < 10) out[OFF_FC2OUT + (size_t)img * 10 + lane] = o2;

    // ---- log_softmax across lanes 0..9 (16-lane butterfly; group 0 valid) ----
    float v = (lane < 10) ? o2 : -3.0e38f;
    #pragma unroll
    for (int d = 1; d < 16; d <<= 1)
        v = fmaxf(v, __shfl_xor(v, d, 16));
    float e = (lane < 10) ? expf(o2 - v) : 0.0f;
    #pragma unroll
    for (int d = 1; d < 16; d <<= 1)
        e += __shfl_xor(e, d, 16);
    float lse = v + logf(e);
    if (lane < 10) out[OFF_LOGP + (size_t)img * 10 + lane] = o2 - lse;
}

extern "C" void kernel_launch(void* const* d_in, const int* in_sizes, int n_in,
                              void* d_out, int out_size, void* d_ws, size_t ws_size,
                              hipStream_t stream) {
    const float* x   = (const float*)d_in[0];
    const float* cw1 = (const float*)d_in[1];
    const float* cb1 = (const float*)d_in[2];
    const float* cw2 = (const float*)d_in[3];
    const float* cb2 = (const float*)d_in[4];
    const float* fw1 = (const float*)d_in[5];
    const float* fb1 = (const float*)d_in[6];
    const float* fw2 = (const float*)d_in[7];
    const float* fb2 = (const float*)d_in[8];
    float* o  = (float*)d_out;
    float* ws = (float*)d_ws;

    k12_convs<<<NB, 512, 0, stream>>>(x, cw1, cb1, cw2, cb2, fw1, fb1, fw2, fb2, ws, o);
    k3_fc    <<<NB / 4, 256, 0, stream>>>(ws, o);
}

// Round 6
// 156.551 us; speedup vs baseline: 1.2984x; 1.0076x over previous
//
#include <hip/hip_runtime.h>
#include <math.h>

// Fixed-point LeNet, B=2048. R15: conv1 i-major task remap.
// R14 residue: 1.04e7 conflict-cycles ~= 28% of k12 time; localized to conv1
// x-reads (t=co*48+i*2+jh puts 24 distinct s_x rows in one wave; rows i,i+8,
// i+16 alias — 8*28≡0 mod 32 — and ANY 16B-aligned stride has this). Fix by
// remap, not layout: t = i*20 + (co*2+jh) -> a wave spans only 4 rows ->
// ~8 unique chunks per LDS instruction (~1 clk), aliasing <=2-way (free).
// Pool pair (i,i+1) is 20 lanes apart (can straddle waves) -> exchange via
// small LDS buffer s_pm + one extra barrier instead of shfl. Bit-identical.
// Phase 2 (ci-split conv2), staging, fc-prep, k3: verbatim R14.
//
// Output layout (fp32, concatenated flat in reference return order):
//   logp[2048,10], conv1_in[2048,784], conv1_out[2048,5760],
//   conv2_in[2048,1440], conv2_out[2048,1280], fc1_in[2048,320],
//   fc1_out[2048,50], fc2_in[2048,50], fc2_out[2048,10]

#define NB 2048

#define OFF_LOGP   0
#define OFF_C1IN   (OFF_LOGP  + NB*10)
#define OFF_C1OUT  (OFF_C1IN  + NB*784)
#define OFF_C2IN   (OFF_C1OUT + NB*5760)
#define OFF_C2OUT  (OFF_C2IN  + NB*1440)
#define OFF_FC1IN  (OFF_C2OUT + NB*1280)
#define OFF_FC1OUT (OFF_FC1IN + NB*320)
#define OFF_FC2IN  (OFF_FC1OUT+ NB*50)
#define OFF_FC2OUT (OFF_FC2IN + NB*50)

#define MAGIC_F 12582912.0f   // 1.5 * 2^23

// Workspace layout (floats): pre-quantized fc weights, written by k12 blocks 0..50.
#define WS_WT1 0         // [320][64] transposed fw1: wT1[k*64+j]=clamp(quant(fw1[j][k])), j>=50 -> 0
#define WS_B1  20480     // [64]
#define WS_WT2 20544     // [50][16] transposed fw2: wT2[k*16+j], j>=10 -> 0
#define WS_B2  21344     // [16]  (total 21360 floats = 85.4 KB)

__device__ __forceinline__ float clamp8(float v) {
    return __builtin_amdgcn_fmed3f(v, -8.0f, 7.0f);
}

// ---------------- K12: conv1 + pool1 + conv2 + pool2, one block per image ----------------
// block=512 (8 waves), grid=NB.
// Phase 1 (conv1): 480 tasks t = i*20 + co*2 + jh (i-major: 4 rows/wave), 12 out each.
//   Pool exchange via s_pm (LDS) + barrier (pair i,i+1 = lanes 20 apart).
// Phase 2 (conv2): 320 tasks t = (co*8+i)*2 + ch; ch = ci-half; 8 outputs each.
__global__ __launch_bounds__(512, 6)
void k12_convs(const float* __restrict__ x,
               const float* __restrict__ cw1, const float* __restrict__ cb1,
               const float* __restrict__ cw2, const float* __restrict__ cb2,
               const float* __restrict__ fw1, const float* __restrict__ fb1,
               const float* __restrict__ fw2, const float* __restrict__ fb2,
               float* __restrict__ ws,
               float* __restrict__ out)
{
    __shared__ __align__(16) float s_w1[280];    // [10][28] padded, quant(w)*256
    __shared__ float s_b1[10];
    __shared__ __align__(16) float s_w2[5600];   // [20*10][28] padded, quant(w)*256
    __shared__ float s_b2[20];
    __shared__ __align__(16) float s_x[784];     // quantized input image
    __shared__ __align__(16) float s_p1[1440];   // pool1 output = conv2 input (LDS handoff)
    __shared__ float s_pm[1440];                 // pool1 partner-max exchange [12*20][6]

    const int t   = threadIdx.x;
    const int img = blockIdx.x;

    // ---- phase 0: stage everything (one barrier) ----
    if (t < 250)                 s_w1[(t/25)*28 + (t%25)] = rintf(cw1[t] * 256.0f);
    else if (t >= 256 && t < 266) s_b1[t - 256] = rintf(cb1[t - 256] * 256.0f);
    else if (t >= 288 && t < 308) s_b2[t - 288] = rintf(cb2[t - 288] * 256.0f);
    for (int idx = t; idx < 5000; idx += 512) {          // conv2 w: 20KB, L2-hit
        int cc = idx / 25, q = idx % 25;                 // cc = co*10+ci
        s_w2[cc * 28 + q] = rintf(cw2[idx] * 256.0f);
    }
    const float* xg = x + (size_t)img * 784;
    float* c1in_g = out + OFF_C1IN + (size_t)img * 784;
    for (int i = t; i < 784; i += 512) {
        float v = rintf(xg[i] * 256.0f) * (1.0f / 256.0f);
        s_x[i] = v;
        c1in_g[i] = v;
    }
    __syncthreads();

    // ---- phase 1: conv1 + pool1 (i-major remap) ----
    int p1_i = 0, p1_c = 0;
    float p1_m[6];
    if (t < 480) {
        const int i  = t / 20;            // 0..23  (4 distinct rows per wave)
        const int c  = t % 20;
        const int co = c >> 1;
        const int jh = c & 1;             // cols [12*jh, 12*jh+12)
        p1_i = i; p1_c = c;

        float wreg[28];
        {
            const float* wb = s_w1 + co * 28;
            #pragma unroll
            for (int k = 0; k < 7; k++) {
                float4 v4 = *(const float4*)(wb + 4 * k);
                wreg[4*k] = v4.x; wreg[4*k+1] = v4.y; wreg[4*k+2] = v4.z; wreg[4*k+3] = v4.w;
            }
        }

        float acc[12];
        #pragma unroll
        for (int j = 0; j < 12; j++) acc[j] = MAGIC_F;   // magic-biased accumulator

        #pragma unroll
        for (int p = 0; p < 5; p++) {
            float xr[16];
            const float* row = &s_x[(i + p) * 28 + 12 * jh];
            #pragma unroll
            for (int k = 0; k < 4; k++) {
                float4 v4 = *(const float4*)(row + 4 * k);
                xr[4*k] = v4.x; xr[4*k+1] = v4.y; xr[4*k+2] = v4.z; xr[4*k+3] = v4.w;
            }
            #pragma unroll
            for (int q = 0; q < 5; q++) {
                float w = wreg[p * 5 + q];
                #pragma unroll
                for (int j = 0; j < 12; j++)
                    acc[j] = fmaf(xr[q + j], w, acc[j]);   // mul+round+add in 1 op
            }
        }
        const float C = MAGIC_F - s_b1[co];   // exact (b256 integer, same exponent)
        float v[12];
        #pragma unroll
        for (int j = 0; j < 12; j++) v[j] = (acc[j] - C) * (1.0f / 256.0f);  // exact grid

        float* gdst = out + OFF_C1OUT + (size_t)img * 5760 + co * 576 + i * 24 + 12 * jh;
        #pragma unroll
        for (int k = 0; k < 3; k++) {
            float4 st = { v[4*k], v[4*k+1], v[4*k+2], v[4*k+3] };
            *(float4*)(gdst + 4 * k) = st;
        }

        #pragma unroll
        for (int j2 = 0; j2 < 6; j2++) p1_m[j2] = fmaxf(v[2*j2], v[2*j2+1]);

        if (i & 1) {   // odd row: publish column-pair maxes for partner
            float* dst = s_pm + ((i >> 1) * 20 + c) * 6;
            #pragma unroll
            for (int j2 = 0; j2 < 6; j2++) dst[j2] = p1_m[j2];
        }
    }
    __syncthreads();

    if (t < 480 && !(p1_i & 1)) {
        const int i  = p1_i;
        const int c  = p1_c;
        const int co = c >> 1;
        const int jh = c & 1;
        const float* src = s_pm + ((i >> 1) * 20 + c) * 6;
        float pr[6];
        #pragma unroll
        for (int j2 = 0; j2 < 6; j2++)
            pr[j2] = fmaxf(fmaxf(p1_m[j2], src[j2]), 0.0f);
        const int o = co * 144 + (i >> 1) * 12 + 6 * jh;
        float* g = out + OFF_C2IN + (size_t)img * 1440 + o;
        #pragma unroll
        for (int k = 0; k < 3; k++) {
            float2 st = { pr[2*k], pr[2*k+1] };
            *(float2*)(g + 2 * k) = st;
            s_p1[o + 2*k]     = pr[2*k];      // LDS handoff to conv2
            s_p1[o + 2*k + 1] = pr[2*k + 1];
        }
    }
    __syncthreads();

    // ---- phase 2: conv2 + pool2, ci-split (5 ci per thread, full 8-col row) ----
    if (t < 320) {
        const int ch = t & 1;              // ci-half: ci = 5*ch + cc
        const int rc = t >> 1;             // co*8 + i
        const int co = rc >> 3;
        const int i  = rc & 7;

        float acc[8];
        #pragma unroll
        for (int j = 0; j < 8; j++) acc[j] = MAGIC_F;

        #pragma unroll
        for (int cc = 0; cc < 5; cc++) {
            const int ci = ch * 5 + cc;
            float wreg[28];
            {
                const float* wb = s_w2 + (co * 10 + ci) * 28;
                #pragma unroll
                for (int k = 0; k < 7; k++) {
                    float4 v4 = *(const float4*)(wb + 4 * k);
                    wreg[4*k] = v4.x; wreg[4*k+1] = v4.y; wreg[4*k+2] = v4.z; wreg[4*k+3] = v4.w;
                }
            }
            const float* xb = s_p1 + ci * 144;
            #pragma unroll
            for (int p = 0; p < 5; p++) {
                const float* row = xb + (i + p) * 12;
                float4 a4 = *(const float4*)(row);
                float4 b4 = *(const float4*)(row + 4);
                float4 c4 = *(const float4*)(row + 8);
                float xr[12] = { a4.x, a4.y, a4.z, a4.w, b4.x, b4.y, b4.z, b4.w,
                                 c4.x, c4.y, c4.z, c4.w };
                #pragma unroll
                for (int q = 0; q < 5; q++) {
                    float w = wreg[p * 5 + q];
                    #pragma unroll
                    for (int j = 0; j < 8; j++)
                        acc[j] = fmaf(xr[q + j], w, acc[j]);   // mul+round+add in 1 op
                }
            }
        }

        // un-bias each partial (exact: same exponent as MAGIC), then integer-exact reduce
        float s[8];
        #pragma unroll
        for (int j = 0; j < 8; j++) s[j] = acc[j] - MAGIC_F;
        #pragma unroll
        for (int j = 0; j < 8; j++) s[j] += __shfl_xor(s[j], 1);   // partner = other ci-half

        const float b2 = s_b2[co];
        float v[8];
        #pragma unroll
        for (int j = 0; j < 8; j++) v[j] = (s[j] + b2) * (1.0f / 256.0f);  // exact grid

        // pool2 (computed by both ch lanes — identical values; partner i^1 = t^2)
        float m[4], pm[4];
        #pragma unroll
        for (int c = 0; c < 4; c++) m[c] = fmaxf(v[2*c], v[2*c+1]);
        #pragma unroll
        for (int c = 0; c < 4; c++) pm[c] = __shfl_xor(m[c], 2);

        if (ch == 0) {
            float4 st0 = { v[0], v[1], v[2], v[3] };
            float4 st1 = { v[4], v[5], v[6], v[7] };
            float* cdst = out + OFF_C2OUT + (size_t)img * 1280 + co * 64 + i * 8;
            *(float4*)(cdst)     = st0;
            *(float4*)(cdst + 4) = st1;

            if ((i & 1) == 0) {
                float4 pr = { fmaxf(fmaxf(m[0], pm[0]), 0.0f),
                              fmaxf(fmaxf(m[1], pm[1]), 0.0f),
                              fmaxf(fmaxf(m[2], pm[2]), 0.0f),
                              fmaxf(fmaxf(m[3], pm[3]), 0.0f) };
                *(float4*)(out + OFF_FC1IN + (size_t)img * 320 + co * 16 + (i >> 1) * 4) = pr;
            }
        }
    }

    // ---- fc weight pre-quant, spread over blocks 0..50 (hidden; no barrier).
    // Stream-ordered: k3 launches after k12 completes, so visibility is guaranteed.
    const int b = blockIdx.x;
    if (b < 50) {
        // wT1 row j=b: coalesced read fw1[b*320 + i], scattered (cheap) write.
        const float* src = fw1 + b * 320;
        for (int i = t; i < 320; i += 512)
            ws[WS_WT1 + i * 64 + b] = clamp8(rintf(src[i] * 256.0f) * (1.0f / 256.0f));
    } else if (b == 50) {
        // zero-fill wT1 cols 50..63
        for (int idx = t; idx < 320 * 14; idx += 512) {
            int i = idx / 14, j = 50 + idx % 14;
            ws[WS_WT1 + i * 64 + j] = 0.0f;
        }
        // wT2[50][16]
        for (int idx = t; idx < 800; idx += 512) {
            int k = idx >> 4, j = idx & 15;
            float v = 0.0f;
            if (j < 10) v = clamp8(rintf(fw2[j * 50 + k] * 256.0f) * (1.0f / 256.0f));
            ws[WS_WT2 + idx] = v;
        }
        if (t < 64) ws[WS_B1 + t] = (t < 50) ? clamp8(rintf(fb1[t] * 256.0f) * (1.0f / 256.0f)) : 0.0f;
        if (t < 16) ws[WS_B2 + t] = (t < 10) ? clamp8(rintf(fb2[t] * 256.0f) * (1.0f / 256.0f)) : 0.0f;
    }
}

// ---------------- K3: fc1 + fc2 + log_softmax, one wave per image ----------------
// block=256 (4 waves = 4 images), grid = NB/4 = 512.
// fc1: lane j<50 owns output j; x broadcast from LDS (same-addr = free),
// weights pre-transposed -> one coalesced 256B load per k. fc2 + softmax via shfl.
__global__ __launch_bounds__(256)
void k3_fc(const float* __restrict__ ws, float* __restrict__ out)
{
    __shared__ float s_x[4][320];

    const int t    = threadIdx.x;
    const int wv   = t >> 6;
    const int lane = t & 63;
    const int img  = blockIdx.x * 4 + wv;

    const float* xg = out + OFF_FC1IN + (size_t)img * 320;   // written by k12
    #pragma unroll
    for (int r = 0; r < 5; r++)
        s_x[wv][lane + 64 * r] = clamp8(xg[lane + 64 * r]);  // round_max(quant(x)) (already on grid)
    __syncthreads();

    // ---- fc1 ----
    float acc = ws[WS_B1 + lane];
    #pragma unroll 8
    for (int k = 0; k < 320; k++)
        acc = fmaf(s_x[wv][k], ws[WS_WT1 + k * 64 + lane], acc);
    float o1 = rintf(clamp8(acc) * 256.0f) * (1.0f / 256.0f);
    float r1 = fmaxf(o1, 0.0f);
    if (lane < 50) {
        out[OFF_FC1OUT + (size_t)img * 50 + lane] = o1;
        out[OFF_FC2IN  + (size_t)img * 50 + lane] = r1;
    }
    float yc = clamp8(r1);                 // valid on lanes 0..49

    // ---- fc2 (y broadcast via shfl with uniform index -> readlane) ----
    float acc2 = ws[WS_B2 + (lane & 15)];
    #pragma unroll 10
    for (int k = 0; k < 50; k++) {
        float yk = __shfl(yc, k);
        acc2 = fmaf(yk, ws[WS_WT2 + k * 16 + (lane & 15)], acc2);
    }
    float o2 = rintf(clamp8(acc2) * 256.0f) * (1.0f / 256.0f);
    if (lane < 10) out[OFF_FC2OUT + (size_t)img * 10 + lane] = o2;

    // ---- log_softmax across lanes 0..9 (16-lane butterfly; group 0 valid) ----
    float v = (lane < 10) ? o2 : -3.0e38f;
    #pragma unroll
    for (int d = 1; d < 16; d <<= 1)
        v = fmaxf(v, __shfl_xor(v, d, 16));
    float e = (lane < 10) ? expf(o2 - v) : 0.0f;
    #pragma unroll
    for (int d = 1; d < 16; d <<= 1)
        e += __shfl_xor(e, d, 16);
    float lse = v + logf(e);
    if (lane < 10) out[OFF_LOGP + (size_t)img * 10 + lane] = o2 - lse;
}

extern "C" void kernel_launch(void* const* d_in, const int* in_sizes, int n_in,
                              void* d_out, int out_size, void* d_ws, size_t ws_size,
                              hipStream_t stream) {
    const float* x   = (const float*)d_in[0];
    const float* cw1 = (const float*)d_in[1];
    const float* cb1 = (const float*)d_in[2];
    const float* cw2 = (const float*)d_in[3];
    const float* cb2 = (const float*)d_in[4];
    const float* fw1 = (const float*)d_in[5];
    const float* fb1 = (const float*)d_in[6];
    const float* fw2 = (const float*)d_in[7];
    const float* fb2 = (const float*)d_in[8];
    float* o  = (float*)d_out;
    float* ws = (float*)d_ws;

    k12_convs<<<NB, 512, 0, stream>>>(x, cw1, cb1, cw2, cb2, fw1, fb1, fw2, fb2, ws, o);
    k3_fc    <<<NB / 4, 256, 0, stream>>>(ws, o);
}